// Round 14
// baseline (178.757 us; speedup 1.0000x reference)
//
#include <hip/hip_runtime.h>

#define KW 11
#define PAD 5
#define TW 64              // tile width (halo overhead 74/64 = 1.16x)
#define TH 64              // tile height: 4 strips of 16 rows (R14)
#define HROWS 16           // rows per strip (phase B row r needs only vv row r)
#define NSTRIP 4
#define ICOLS 74           // input col span incl. halo (TW + KW - 1)
#define S4 77              // f4-plane row stride
#define SX 77              // sx-plane row stride
#define IMH 512
#define IMW 512
#define NBLK 3072          // 8 x 8 x 48
#define NCONV 296          // ICOLS*4 phase-A conv tasks
#define LBASE 320          // loader threads start (wave-aligned: waves 5..7)
#define NLOAD 192          // loader thread count
#define RAWROWS 26         // strip input rows union (16 out + 10 halo)
#define RAWV (2*RAWROWS*74)   // 3848 raw values (img-interleaved)
#define LTASK 21           // ceil(3848/192)

typedef float f2 __attribute__((ext_vector_type(2)));
typedef float f4 __attribute__((ext_vector_type(4)));

// LDS: vv4[row*S4+col] = (mu1,mu2,q11,q22) f4; vsx = x1*x2; raw = staged
// strip input, img-interleaved raw[2*(row*74+col)+img]. Single raw buffer.
// Schedule (strips s0..s3): conv(t<296) computes; loaders(t>=320) stage s+1
// with ISSUE-EARLY (during A phases) / WRITE-LATE (during B phases — B never
// reads raw; a barrier separates A(raw s) from the s+1 overwrite):
//   top: conv reg-load s0 | loaders issue+write s1
//   bar | A0(regs)        | loaders issue s2
//   bar | B0
//   bar | A1(raw s1)
//   bar | loaders write s2 ; B1
//   bar | A2(raw s2)      | loaders issue s3
//   bar | loaders write s3 ; B2
//   bar | A3(raw s3)
//   bar | B3 ; reduce
//
// R6: reg-hoisted loads (MLP) = the lever. R8: never DEMAND occupancy via
// launch_bounds min-waves (spill disaster); WRITE_SIZE > ~1 MB = spill alarm.
// R10: compiler sinks same-thread prefetch -> cross-thread staging instead.
// R12: bank-conflict counter is ~1.2k cyc/block constant, not load-bearing.
// R13: producer waves staging strip1 -> 71 us. R14: deepen to 4 strips:
// exposed first-strip HBM 1:1 -> 1:3, prep/reduction amortize over 2x.

#define A_LOAD(EDGE_)                                                         \
    if (t < NCONV) {                                                          \
        const int gr0 = iy0 + ar0;                                            \
        if (EDGE_) {                                                          \
            const bool cok = (agc >= 0) && (agc < IMW);                       \
            _Pragma("unroll")                                                 \
            for (int i = 0; i < 14; ++i) {                                    \
                const int gr = gr0 + i;                                       \
                const bool ok = cok && (gr >= 0) && (gr < IMH);               \
                const size_t o = base + (size_t)(ok ? gr : 0) * IMW           \
                               + (ok ? agc : 0);                              \
                p1[i] = ok ? img1[o] : 0.f;                                   \
                p2[i] = ok ? img2[o] : 0.f;                                   \
            }                                                                 \
        } else {                                                              \
            _Pragma("unroll")                                                 \
            for (int i = 0; i < 14; ++i) {                                    \
                const size_t o = base + (size_t)(gr0 + i) * IMW + agc;        \
                p1[i] = img1[o];                                              \
                p2[i] = img2[o];                                              \
            }                                                                 \
        }                                                                     \
    }

// Loader issue: strip S_ input union into rv[] regs. o = lidx + 192*s;
// img = o&1, row = o/148, col = (o%148)>>1. For S_>=1, gr >= 11 (no top chk).
#define RAW_ISSUE(EDGE_, S_)                                                  \
    {                                                                         \
        const int iyS = iy0 + (S_) * HROWS;                                   \
        _Pragma("unroll")                                                     \
        for (int s = 0; s < LTASK; ++s) {                                     \
            const int o = lidx + NLOAD * s;                                   \
            const int row = o / 148;                                          \
            const int col = (o % 148) >> 1;                                   \
            const int gr = iyS + row;                                         \
            const int gc = ix0 + col;                                         \
            const float* sp = (o & 1) ? img2 : img1;                          \
            bool ok = (s != LTASK - 1) || (o < RAWV);                         \
            if (EDGE_) ok = ok && (gr < IMH) && (gc >= 0) && (gc < IMW);      \
            const size_t go = base + (size_t)(ok ? gr : 0) * IMW              \
                            + (ok ? gc : 0);                                  \
            rv[s] = ok ? sp[go] : 0.f;                                        \
        }                                                                     \
    }

#define RAW_WRITE                                                             \
    {                                                                         \
        _Pragma("unroll")                                                     \
        for (int s = 0; s < LTASK; ++s) {                                     \
            const int o = lidx + NLOAD * s;                                   \
            if (s != LTASK - 1 || o < RAWV) raw[o] = rv[s];                   \
        }                                                                     \
    }

// Shared conv body: consumes x12 (f2 per row i), writes vv4/vsx.
#define A_CONV_BODY(GETX_)                                                    \
    {                                                                         \
        f2 m12[4]  = {{0,0},{0,0},{0,0},{0,0}};                               \
        f2 qq[4]   = {{0,0},{0,0},{0,0},{0,0}};                               \
        f2 sx01 = {0, 0}, sx23 = {0, 0};                                      \
        _Pragma("unroll")                                                     \
        for (int i = 0; i < 14; ++i) {                                        \
            f2 x12; GETX_;                                                    \
            const f2 sq = x12 * x12;                                          \
            const float sxy = x12.x * x12.y;                                  \
            f2 sxy2; sxy2.x = sxy; sxy2.y = sxy;                              \
            _Pragma("unroll")                                                 \
            for (int k = 0; k < 4; ++k) {                                     \
                const int j = i - k;                                          \
                if (j >= 0 && j < KW) {                                       \
                    const float w = wg[j];   /* SGPR operand */               \
                    const f2 w2 = {w, w};                                     \
                    m12[k] += w2 * x12;          /* v_pk_fma_f32 */           \
                    qq[k]  += w2 * sq;           /* v_pk_fma_f32 */           \
                }                                                             \
            }                                                                 \
            if (i >= 1 && i <= 10)       sx01 += wp[i] * sxy2;                \
            else if (i == 0)             sx01.x += wg[0]  * sxy;              \
            else if (i == 11)            sx01.y += wg[10] * sxy;              \
            if (i >= 3 && i <= 12)       sx23 += wp[i - 2] * sxy2;            \
            else if (i == 2)             sx23.x += wg[0]  * sxy;              \
            else if (i == 13)            sx23.y += wg[10] * sxy;              \
        }                                                                     \
        const float sxs[4] = {sx01.x, sx01.y, sx23.x, sx23.y};                \
        _Pragma("unroll")                                                     \
        for (int k = 0; k < 4; ++k) {                                         \
            f4 v;                                                             \
            v.x = m12[k].x; v.y = m12[k].y;                                   \
            v.z = qq[k].x;  v.w = qq[k].y;                                    \
            vv4[(ar0 + k) * S4 + ac] = v;        /* ds_write_b128 */          \
            vsx[(ar0 + k) * SX + ac] = sxs[k];   /* ds_write_b32  */          \
        }                                                                     \
    }

// Phase B: 2 output cols per thread, row = t&15, cp = t>>4; packed-wt sx.
#define PHASE_B                                                               \
    {                                                                         \
        const int row = t & 15;                                               \
        const int cp  = t >> 4;              /* 0..31 */                      \
        const f4* __restrict__ p4 = &vv4[row * S4 + cp * 2];                  \
        const float* __restrict__ px = &vsx[row * SX + cp * 2];               \
        f2 am12[2] = {{0,0},{0,0}};                                           \
        f2 aqq[2]  = {{0,0},{0,0}};                                           \
        f2 asxp = {0, 0};                                                     \
        _Pragma("unroll")                                                     \
        for (int b = 0; b < 3; ++b) {                                         \
            f4 v[4]; float vx[4];                                             \
            _Pragma("unroll")                                                 \
            for (int cc = 0; cc < 4; ++cc) {                                  \
                v[cc]  = p4[b * 4 + cc];                                      \
                vx[cc] = px[b * 4 + cc];                                      \
            }                                                                 \
            _Pragma("unroll")                                                 \
            for (int cc = 0; cc < 4; ++cc) {                                  \
                const int cg = b * 4 + cc;                                    \
                f2 v12; v12.x = v[cc].x; v12.y = v[cc].y;                     \
                f2 vqq; vqq.x = v[cc].z; vqq.y = v[cc].w;                     \
                _Pragma("unroll")                                             \
                for (int k = 0; k < 2; ++k) {                                 \
                    const int j = cg - k;                                     \
                    if (j >= 0 && j < KW) {                                   \
                        const float w = wg[j];                                \
                        const f2 w2 = {w, w};                                 \
                        am12[k] += w2 * v12;                                  \
                        aqq[k]  += w2 * vqq;                                  \
                    }                                                         \
                }                                                             \
                f2 vx2; vx2.x = vx[cc]; vx2.y = vx[cc];                       \
                if (cg >= 1 && cg <= 10)  asxp += wp[cg] * vx2;               \
                else if (cg == 0)         asxp.x += wg[0]  * vx[cc];          \
                else if (cg == 11)        asxp.y += wg[10] * vx[cc];          \
            }                                                                 \
        }                                                                     \
        const float asx[2] = {asxp.x, asxp.y};                                \
        _Pragma("unroll")                                                     \
        for (int k = 0; k < 2; ++k) {                                         \
            const float mu1 = am12[k].x, mu2 = am12[k].y;                     \
            const float mu1sq = mu1 * mu1, mu2sq = mu2 * mu2;                 \
            const float mu12 = mu1 * mu2;                                     \
            const float sig1 = aqq[k].x - mu1sq;                              \
            const float sig2 = aqq[k].y - mu2sq;                              \
            const float sig12 = asx[k] - mu12;                                \
            const float num = (2.f * mu12 + C1v) * (2.f * sig12 + C2v);       \
            const float den = (mu1sq + mu2sq + C1v) * (sig1 + sig2 + C2v);    \
            float r = __builtin_amdgcn_rcpf(den);                             \
            r = r * (2.f - den * r);             /* Newton -> ~fp32 exact */  \
            lsum += num * r;                                                  \
        }                                                                     \
    }

__global__ __launch_bounds__(512, 4) void ssim_main(
    const float* __restrict__ img1, const float* __restrict__ img2,
    const float* __restrict__ window, float* __restrict__ partial)
{
    __shared__ f4 vv4[HROWS * S4];                 // 19712 B
    __shared__ float vsx[HROWS * SX];              //  4928 B
    __shared__ __align__(16) float raw[RAWV];      // 15392 B -> ~40.1 KB
    __shared__ float g[KW];
    __shared__ float wsum[8];

    const int t = threadIdx.x;

    const int plane = blockIdx.z;
    const size_t base = (size_t)plane * IMH * IMW;
    const int ix0 = blockIdx.x * TW - PAD;
    const int iy0 = blockIdx.y * TH - PAD;

    const int ac  = t % ICOLS;                    // conv col (valid t < NCONV)
    const int ar0 = (t / ICOLS) * 4;              // conv local row base
    const int agc = ix0 + ac;
    const int lidx = t - LBASE;                   // loader index (t >= LBASE)

    const bool interior = (ix0 >= 0) && (ix0 + ICOLS <= IMW) &&
                          (iy0 >= 0) && (iy0 + TH + KW - 1 <= IMH);

    float p1[14], p2[14];                         // strip-0 reg inputs (conv)
    float rv[LTASK];                              // staging regs (loaders)

    // Top: conv threads reg-load strip 0; loaders issue+write strip 1.
    if (t < LBASE) {
        if (interior) { A_LOAD(false) } else { A_LOAD(true) }
    } else {
        if (interior) { RAW_ISSUE(false, 1) } else { RAW_ISSUE(true, 1) }
        RAW_WRITE                                 // raw unused yet: write now
    }

    // Separable 1D Gaussian = row-sums of the 2D window (columns sum to 1).
    if (t < KW) {
        float s = 0.f;
        for (int j = 0; j < KW; ++j) s += window[(t * KW + j) * 3];
        g[t] = s;
    }
    __syncthreads();                              // bar1

    // Weights wave-uniform -> SGPRs; packed pairs for pk-fma sx.
    float wg[KW];
#pragma unroll
    for (int j = 0; j < KW; ++j) {
        const int bi = __builtin_amdgcn_readfirstlane(__float_as_int(g[j]));
        wg[j] = __int_as_float(bi);
    }
    f2 wp[KW];
#pragma unroll
    for (int j = 1; j < KW; ++j) { wp[j].x = wg[j]; wp[j].y = wg[j - 1]; }

    const float C1v = 0.0001f;
    const float C2v = 0.0009f;
    float lsum = 0.f;

    // ---- Strip 0: conv from regs; loaders issue strip-2 loads ----
    if (t < NCONV) A_CONV_BODY(x12.x = p1[i]; x12.y = p2[i];)
    else if (t >= LBASE) {
        if (interior) { RAW_ISSUE(false, 2) } else { RAW_ISSUE(true, 2) }
    }
    __syncthreads();                              // bar2
    PHASE_B                                       // strip 0
    __syncthreads();                              // bar3

    // ---- Strip 1: conv from raw ----
    if (t < NCONV)
        A_CONV_BODY(x12 = *reinterpret_cast<const f2*>(
                        &raw[((ar0 + i) * 74 + ac) * 2]);)
    __syncthreads();                              // bar4 (s1 reads done)
    if (t >= LBASE) RAW_WRITE                     // write strip 2
    PHASE_B                                       // strip 1
    __syncthreads();                              // bar5

    // ---- Strip 2: conv from raw; loaders issue strip-3 loads ----
    if (t < NCONV)
        A_CONV_BODY(x12 = *reinterpret_cast<const f2*>(
                        &raw[((ar0 + i) * 74 + ac) * 2]);)
    else if (t >= LBASE) {
        if (interior) { RAW_ISSUE(false, 3) } else { RAW_ISSUE(true, 3) }
    }
    __syncthreads();                              // bar6 (s2 reads done)
    if (t >= LBASE) RAW_WRITE                     // write strip 3
    PHASE_B                                       // strip 2
    __syncthreads();                              // bar7

    // ---- Strip 3: conv from raw ----
    if (t < NCONV)
        A_CONV_BODY(x12 = *reinterpret_cast<const f2*>(
                        &raw[((ar0 + i) * 74 + ac) * 2]);)
    __syncthreads();                              // bar8
    PHASE_B                                       // strip 3

    // ---- Reduction: wave shuffle -> cross-wave LDS -> per-block store.
#pragma unroll
    for (int off = 32; off > 0; off >>= 1) lsum += __shfl_down(lsum, off, 64);
    if ((t & 63) == 0) wsum[t >> 6] = lsum;
    __syncthreads();
    if (t == 0) {
        float bs = 0.f;
#pragma unroll
        for (int w = 0; w < 8; ++w) bs += wsum[w];
        unsigned bid = (blockIdx.z * gridDim.y + blockIdx.y) * gridDim.x
                     + blockIdx.x;
        partial[bid] = bs;
    }
}

__global__ __launch_bounds__(1024) void ssim_reduce(
    const float* __restrict__ partial, float* __restrict__ out, double inv_n)
{
    __shared__ double dsum[16];
    const int t = threadIdx.x;
    double s = 0.0;
    for (int i = t; i < NBLK; i += 1024) s += (double)partial[i];
#pragma unroll
    for (int off = 32; off > 0; off >>= 1) s += __shfl_down(s, off, 64);
    if ((t & 63) == 0) dsum[t >> 6] = s;
    __syncthreads();
    if (t == 0) {
        double tot = 0.0;
#pragma unroll
        for (int w = 0; w < 16; ++w) tot += dsum[w];
        out[0] = (float)(tot * inv_n);
    }
}

extern "C" void kernel_launch(void* const* d_in, const int* in_sizes, int n_in,
                              void* d_out, int out_size, void* d_ws, size_t ws_size,
                              hipStream_t stream) {
    const float* img1   = (const float*)d_in[0];
    const float* img2   = (const float*)d_in[1];
    const float* window = (const float*)d_in[2];
    float* out = (float*)d_out;
    float* partial = (float*)d_ws;               // 3072 floats = 12 KB

    const int nplanes = in_sizes[0] / (IMH * IMW);   // 48
    const long long total = (long long)in_sizes[0];

    dim3 grid(IMW / TW, IMH / TH, nplanes);      // 8 x 8 x 48 = 3072
    ssim_main<<<grid, 512, 0, stream>>>(img1, img2, window, partial);
    ssim_reduce<<<1, 1024, 0, stream>>>(partial, out, 1.0 / (double)total);
}

// Round 15
// 157.208 us; speedup vs baseline: 1.1371x; 1.1371x over previous
//
#include <hip/hip_runtime.h>

#define KW 11
#define PAD 5
#define TW 64              // tile width (halo overhead 74/64 = 1.16x)
#define TH 32              // two strips of 16 rows (R14 depth-4 regressed: phase-aligned troughs)
#define HROWS 16           // rows per strip (phase B row r needs only vv row r)
#define ICOLS 74           // input col span incl. halo (TW + KW - 1)
#define S4 77              // f4-plane row stride
#define SX 78              // sx-plane row stride (EVEN -> f2-aligned B reads; R15)
#define IMH 512
#define IMW 512
#define NBLK 6144          // 8 x 16 x 48
#define NCONV 296          // ICOLS*4 phase-A conv tasks
#define LBASE 320          // loader threads start (wave-aligned: waves 5..7)
#define NLOAD 192          // loader thread count
#define RAWROWS 26         // strip-1 input rows union (16 out + 10 halo)
#define RAWV (2*RAWROWS*74)   // 3848 raw values (img-interleaved)
#define LTASK 21           // ceil(3848/192)

typedef float f2 __attribute__((ext_vector_type(2)));
typedef float f4 __attribute__((ext_vector_type(4)));

// LDS: vv4[row*S4+col] = (mu1,mu2,q11,q22) f4; vsx = x1*x2; raw = strip-1
// input, img-interleaved raw[2*(row*74+col)+img].
// Schedule: convs(t<296): A0.load(reg) -> A0.conv | loaders(t>=320): raw
// load -> LDS | bar | B0(all) | bar | A1.conv reads raw | bar | B1.
//
// R6: reg-hoisted loads (MLP) = the lever. R8: never DEMAND occupancy
// (min-waves spill disaster); WRITE_SIZE > ~1 MB = spill alarm.
// R10: compiler sinks same-thread prefetch -> cross-thread staging (R13).
// R12: bank-conflict counter ~constant, benign (data-volume floor).
// R13: producer waves stage strip 1 -> 71.3 us, occ 71%. BEST.
// R14: depth-4 strips regressed (94 us): busy time identical, stalls 2x --
// long phase-aligned blocks create whole-CU troughs. Depth 2 is right.
// R15: R13 + SX=78 (even): phase-B sx reads as 6 ds_read_b64 instead of
// 12 ds_read_b32 (-6.1k issue slots/block). vsx __align__(16) for f2 casts.

#define A_LOAD(EDGE_)                                                         \
    if (t < NCONV) {                                                          \
        const int gr0 = iy0 + ar0;                                            \
        if (EDGE_) {                                                          \
            const bool cok = (agc >= 0) && (agc < IMW);                       \
            _Pragma("unroll")                                                 \
            for (int i = 0; i < 14; ++i) {                                    \
                const int gr = gr0 + i;                                       \
                const bool ok = cok && (gr >= 0) && (gr < IMH);               \
                const size_t o = base + (size_t)(ok ? gr : 0) * IMW           \
                               + (ok ? agc : 0);                              \
                p1[i] = ok ? img1[o] : 0.f;                                   \
                p2[i] = ok ? img2[o] : 0.f;                                   \
            }                                                                 \
        } else {                                                              \
            _Pragma("unroll")                                                 \
            for (int i = 0; i < 14; ++i) {                                    \
                const size_t o = base + (size_t)(gr0 + i) * IMW + agc;        \
                p1[i] = img1[o];                                              \
                p2[i] = img2[o];                                              \
            }                                                                 \
        }                                                                     \
    }

// Loaders: 21 tasks each, o = lidx + 192*s; img = o&1 (per-thread constant
// since 192 even), row = o/148, col = (o%148)>>1. Only s==20 can exceed RAWV.
#define RAW_STAGE(EDGE_)                                                      \
    {                                                                         \
        float rv[LTASK];                                                      \
        _Pragma("unroll")                                                     \
        for (int s = 0; s < LTASK; ++s) {                                     \
            const int o = lidx + NLOAD * s;                                   \
            const int row = o / 148;                                          \
            const int col = (o % 148) >> 1;                                   \
            const int gr = iy1 + row;       /* iy1 >= 11: no top check */     \
            const int gc = ix0 + col;                                         \
            const float* sp = (o & 1) ? img2 : img1;                          \
            bool ok = (s != LTASK - 1) || (o < RAWV);                         \
            if (EDGE_) ok = ok && (gr < IMH) && (gc >= 0) && (gc < IMW);      \
            const size_t go = base + (size_t)(ok ? gr : 0) * IMW              \
                            + (ok ? gc : 0);                                  \
            rv[s] = ok ? sp[go] : 0.f;                                        \
        }                                                                     \
        _Pragma("unroll")                                                     \
        for (int s = 0; s < LTASK; ++s) {                                     \
            const int o = lidx + NLOAD * s;                                   \
            if (s != LTASK - 1 || o < RAWV) raw[o] = rv[s];                   \
        }                                                                     \
    }

// Shared conv body: consumes x12 (f2 per row i), writes vv4/vsx.
#define A_CONV_BODY(GETX_)                                                    \
    {                                                                         \
        f2 m12[4]  = {{0,0},{0,0},{0,0},{0,0}};                               \
        f2 qq[4]   = {{0,0},{0,0},{0,0},{0,0}};                               \
        f2 sx01 = {0, 0}, sx23 = {0, 0};                                      \
        _Pragma("unroll")                                                     \
        for (int i = 0; i < 14; ++i) {                                        \
            f2 x12; GETX_;                                                    \
            const f2 sq = x12 * x12;                                          \
            const float sxy = x12.x * x12.y;                                  \
            f2 sxy2; sxy2.x = sxy; sxy2.y = sxy;                              \
            _Pragma("unroll")                                                 \
            for (int k = 0; k < 4; ++k) {                                     \
                const int j = i - k;                                          \
                if (j >= 0 && j < KW) {                                       \
                    const float w = wg[j];   /* SGPR operand */               \
                    const f2 w2 = {w, w};                                     \
                    m12[k] += w2 * x12;          /* v_pk_fma_f32 */           \
                    qq[k]  += w2 * sq;           /* v_pk_fma_f32 */           \
                }                                                             \
            }                                                                 \
            if (i >= 1 && i <= 10)       sx01 += wp[i] * sxy2;                \
            else if (i == 0)             sx01.x += wg[0]  * sxy;              \
            else if (i == 11)            sx01.y += wg[10] * sxy;              \
            if (i >= 3 && i <= 12)       sx23 += wp[i - 2] * sxy2;            \
            else if (i == 2)             sx23.x += wg[0]  * sxy;              \
            else if (i == 13)            sx23.y += wg[10] * sxy;              \
        }                                                                     \
        const float sxs[4] = {sx01.x, sx01.y, sx23.x, sx23.y};                \
        _Pragma("unroll")                                                     \
        for (int k = 0; k < 4; ++k) {                                         \
            f4 v;                                                             \
            v.x = m12[k].x; v.y = m12[k].y;                                   \
            v.z = qq[k].x;  v.w = qq[k].y;                                    \
            vv4[(ar0 + k) * S4 + ac] = v;        /* ds_write_b128 */          \
            vsx[(ar0 + k) * SX + ac] = sxs[k];   /* ds_write_b32  */          \
        }                                                                     \
    }

// Phase B: 2 output cols per thread, row = t&15, cp = t>>4; packed-wt sx.
// sx plane read as 6 f2 (b64): base word 78*row + 2*cp is EVEN -> aligned.
#define PHASE_B(H_)                                                           \
    {                                                                         \
        const int row = t & 15;                                               \
        const int cp  = t >> 4;              /* 0..31 */                      \
        const f4* __restrict__ p4 = &vv4[row * S4 + cp * 2];                  \
        const f2* __restrict__ px2 =                                          \
            reinterpret_cast<const f2*>(&vsx[row * SX + cp * 2]);             \
        f2 am12[2] = {{0,0},{0,0}};                                           \
        f2 aqq[2]  = {{0,0},{0,0}};                                           \
        f2 asxp = {0, 0};                                                     \
        _Pragma("unroll")                                                     \
        for (int b = 0; b < 3; ++b) {                                         \
            f4 v[4]; f2 vp[2];                                                \
            _Pragma("unroll")                                                 \
            for (int cc = 0; cc < 4; ++cc) v[cc] = p4[b * 4 + cc];            \
            vp[0] = px2[b * 2];                                               \
            vp[1] = px2[b * 2 + 1];                                           \
            _Pragma("unroll")                                                 \
            for (int cc = 0; cc < 4; ++cc) {                                  \
                const int cg = b * 4 + cc;                                    \
                const float vxc = (cc & 1) ? vp[cc >> 1].y : vp[cc >> 1].x;   \
                f2 v12; v12.x = v[cc].x; v12.y = v[cc].y;                     \
                f2 vqq; vqq.x = v[cc].z; vqq.y = v[cc].w;                     \
                _Pragma("unroll")                                             \
                for (int k = 0; k < 2; ++k) {                                 \
                    const int j = cg - k;                                     \
                    if (j >= 0 && j < KW) {                                   \
                        const float w = wg[j];                                \
                        const f2 w2 = {w, w};                                 \
                        am12[k] += w2 * v12;                                  \
                        aqq[k]  += w2 * vqq;                                  \
                    }                                                         \
                }                                                             \
                f2 vx2; vx2.x = vxc; vx2.y = vxc;                             \
                if (cg >= 1 && cg <= 10)  asxp += wp[cg] * vx2;               \
                else if (cg == 0)         asxp.x += wg[0]  * vxc;             \
                else if (cg == 11)        asxp.y += wg[10] * vxc;             \
            }                                                                 \
        }                                                                     \
        const float asx[2] = {asxp.x, asxp.y};                                \
        _Pragma("unroll")                                                     \
        for (int k = 0; k < 2; ++k) {                                         \
            const float mu1 = am12[k].x, mu2 = am12[k].y;                     \
            const float mu1sq = mu1 * mu1, mu2sq = mu2 * mu2;                 \
            const float mu12 = mu1 * mu2;                                     \
            const float sig1 = aqq[k].x - mu1sq;                              \
            const float sig2 = aqq[k].y - mu2sq;                              \
            const float sig12 = asx[k] - mu12;                                \
            const float num = (2.f * mu12 + C1v) * (2.f * sig12 + C2v);       \
            const float den = (mu1sq + mu2sq + C1v) * (sig1 + sig2 + C2v);    \
            float r = __builtin_amdgcn_rcpf(den);                             \
            r = r * (2.f - den * r);             /* Newton -> ~fp32 exact */  \
            lsum += num * r;                                                  \
        }                                                                     \
    }

__global__ __launch_bounds__(512, 4) void ssim_main(
    const float* __restrict__ img1, const float* __restrict__ img2,
    const float* __restrict__ window, float* __restrict__ partial)
{
    __shared__ f4 vv4[HROWS * S4];                      // 19712 B
    __shared__ __align__(16) float vsx[HROWS * SX];     //  4992 B
    __shared__ __align__(16) float raw[RAWV];           // 15392 B -> ~40.2 KB
    __shared__ float g[KW];
    __shared__ float wsum[8];

    const int t = threadIdx.x;

    const int plane = blockIdx.z;
    const size_t base = (size_t)plane * IMH * IMW;
    const int ix0 = blockIdx.x * TW - PAD;
    const int iy0 = blockIdx.y * TH - PAD;
    const int iy1 = iy0 + HROWS;                  // first strip-1 input row (>= 11)

    const int ac  = t % ICOLS;                    // conv col (valid t < NCONV)
    const int ar0 = (t / ICOLS) * 4;              // conv local row base
    const int agc = ix0 + ac;
    const int lidx = t - LBASE;                   // loader index (t >= LBASE)

    const bool interior = (ix0 >= 0) && (ix0 + ICOLS <= IMW) &&
                          (iy0 >= 0) && (iy0 + TH + KW - 1 <= IMH);

    float p1[14], p2[14];                         // strip-0 reg inputs (conv)

    // Conv threads issue strip-0 loads; loader waves (5..7) stage strip 1.
    if (t < LBASE) {
        if (interior) { A_LOAD(false) } else { A_LOAD(true) }
    } else {
        if (interior) { RAW_STAGE(false) } else { RAW_STAGE(true) }
    }

    // Separable 1D Gaussian = row-sums of the 2D window (columns sum to 1).
    if (t < KW) {
        float s = 0.f;
        for (int j = 0; j < KW; ++j) s += window[(t * KW + j) * 3];
        g[t] = s;
    }
    __syncthreads();

    // Weights wave-uniform -> SGPRs (VALU reads one SGPR operand free).
    float wg[KW];
#pragma unroll
    for (int j = 0; j < KW; ++j) {
        const int bi = __builtin_amdgcn_readfirstlane(__float_as_int(g[j]));
        wg[j] = __int_as_float(bi);
    }
    // Packed weight pairs wp[j] = {w[j], w[j-1]} for pk-fma sx accumulation.
    f2 wp[KW];
#pragma unroll
    for (int j = 1; j < KW; ++j) { wp[j].x = wg[j]; wp[j].y = wg[j - 1]; }

    const float C1v = 0.0001f;
    const float C2v = 0.0009f;
    float lsum = 0.f;

    // ---- Strip 0 conv (from regs) ----
    if (t < NCONV) A_CONV_BODY(x12.x = p1[i]; x12.y = p2[i];)
    __syncthreads();

    PHASE_B(0)
    __syncthreads();

    // ---- Strip 1 conv (from raw LDS: f2 img-interleaved reads) ----
    if (t < NCONV)
        A_CONV_BODY(x12 = *reinterpret_cast<const f2*>(
                        &raw[((ar0 + i) * 74 + ac) * 2]);)
    __syncthreads();

    PHASE_B(1)

    // ---- Reduction: wave shuffle -> cross-wave LDS -> per-block store.
#pragma unroll
    for (int off = 32; off > 0; off >>= 1) lsum += __shfl_down(lsum, off, 64);
    if ((t & 63) == 0) wsum[t >> 6] = lsum;
    __syncthreads();
    if (t == 0) {
        float bs = 0.f;
#pragma unroll
        for (int w = 0; w < 8; ++w) bs += wsum[w];
        unsigned bid = (blockIdx.z * gridDim.y + blockIdx.y) * gridDim.x
                     + blockIdx.x;
        partial[bid] = bs;
    }
}

__global__ __launch_bounds__(1024) void ssim_reduce(
    const float* __restrict__ partial, float* __restrict__ out, double inv_n)
{
    __shared__ double dsum[16];
    const int t = threadIdx.x;
    double s = 0.0;
    for (int i = t; i < NBLK; i += 1024) s += (double)partial[i];
#pragma unroll
    for (int off = 32; off > 0; off >>= 1) s += __shfl_down(s, off, 64);
    if ((t & 63) == 0) dsum[t >> 6] = s;
    __syncthreads();
    if (t == 0) {
        double tot = 0.0;
#pragma unroll
        for (int w = 0; w < 16; ++w) tot += dsum[w];
        out[0] = (float)(tot * inv_n);
    }
}

extern "C" void kernel_launch(void* const* d_in, const int* in_sizes, int n_in,
                              void* d_out, int out_size, void* d_ws, size_t ws_size,
                              hipStream_t stream) {
    const float* img1   = (const float*)d_in[0];
    const float* img2   = (const float*)d_in[1];
    const float* window = (const float*)d_in[2];
    float* out = (float*)d_out;
    float* partial = (float*)d_ws;               // 6144 floats = 24 KB

    const int nplanes = in_sizes[0] / (IMH * IMW);   // 48
    const long long total = (long long)in_sizes[0];

    dim3 grid(IMW / TW, IMH / TH, nplanes);      // 8 x 16 x 48 = 6144
    ssim_main<<<grid, 512, 0, stream>>>(img1, img2, window, partial);
    ssim_reduce<<<1, 1024, 0, stream>>>(partial, out, 1.0 / (double)total);
}